// Round 9
// baseline (359.552 us; speedup 1.0000x reference)
//
#include <hip/hip_runtime.h>
#include <stdint.h>

// LIF spike encoder — two-phase, bit-exact fp32.
//   R4 fused 320us | R5 split dense 243 (latency-starved) | R6 154 (n-fast
//   grid = XCD-local W, but 8 redundant wave-streams through L1) | R7 275
//   (m-fast grid broke XCD locality, FETCH 4x) | R8 256 (more waves = more
//   redundant L1 bytes; model: ~25 B/cyc/CU L1-issue bound).
//   R9 (this): kill the redundancy. W tile staged ONCE per block into LDS
//   (dbuf, reg-prefetch, 1 barrier/tile); compute reads W from LDS b32
//   lane-consecutive (conflict-free); x via wave-uniform pointers
//   (readfirstlane -> scalar path); 8 rows/thread so each W value feeds
//   8 FMAs -> VALU-bound (~15us floor), L1 bytes/CU 16.8MB -> ~2MB.
// Bit-exactness: each output = ONE register, fmaf over k=0..2047 ascending
// (tiles ascend, k-within-tile ascends) — identical chain to all passing
// rounds. Sparse phase: ordered adds over sorted spike list == dense chain.

#define BATCHSZ 256
#define NU      2048
#define TSTEPS  128
#define BLK     1024
#define NWAVES  (BLK / 64)

// ---------------- Phase A: dense GEMM (t=1), bit-exact chain ----------------
// grid (32 n-tiles fast, 16 m-tiles), block 128 thr (2 waves).
// wave w: rows m0+8w..m0+8w+7, cols n0+lane (BN=64). BK=32 double-buffered.
#define A_BK 32
#define A_NT (NU / A_BK)     // 64 k-tiles

__global__ __launch_bounds__(128) void lif_dense_v1(
    const float* __restrict__ x,
    const float* __restrict__ W,
    float* __restrict__ ws)
{
    __shared__ float s_w[2][A_BK * 64];      // 2 x 8 KB W tiles

    const int tid  = threadIdx.x;
    const int lane = tid & 63;
    const int n0   = blockIdx.x * 64;        // n-tile FAST: xcd = bid%8 ->
    const int m0   = blockIdx.y * 16;        //   per-XCD W slice = 2 MB (L2)

    // wave-uniform row base (readfirstlane -> SGPR -> scalar-path x loads)
    const int wu = __builtin_amdgcn_readfirstlane(tid >> 6);   // 0..1
    const float* xp = x + (size_t)(m0 + 8 * wu) * NU;

    float4 pf[4];                            // staging prefetch regs (64 B)

    // stage tile `t` into pf: flat float4 f = j*128+tid; row=f>>4, col4=f&15
    auto stage_load = [&](int t) {
        const float* src = W + (size_t)(t * A_BK) * NU + n0;
        #pragma unroll
        for (int j = 0; j < 4; ++j) {
            int f   = j * 128 + tid;
            int row = f >> 4;
            int c4  = f & 15;
            pf[j] = *(const float4*)(src + (size_t)row * NU + c4 * 4);
        }
    };
    auto stage_write = [&](int buf) {
        float4* dst = (float4*)&s_w[buf][0];
        #pragma unroll
        for (int j = 0; j < 4; ++j) dst[j * 128 + tid] = pf[j];
    };

    // prologue: tile 0 -> buf0; tile 1 in flight
    stage_load(0);
    stage_write(0);
    __syncthreads();
    stage_load(1);

    float acc[8];
    #pragma unroll
    for (int r = 0; r < 8; ++r) acc[r] = 0.0f;

    for (int t = 0; t < A_NT; ++t) {
        const float* wt = &s_w[t & 1][0];
        const int    kb = t * A_BK;

        #pragma unroll
        for (int k4 = 0; k4 < A_BK / 4; ++k4) {
            // 8 wave-uniform float4 x loads (scalar path), reused over 4 k
            float4 xq[8];
            #pragma unroll
            for (int r = 0; r < 8; ++r)
                xq[r] = *(const float4*)(xp + (size_t)r * NU + kb + k4 * 4);
            const float* xqf = (const float*)&xq[0];

            #pragma unroll
            for (int kk = 0; kk < 4; ++kk) {
                float wv = wt[(k4 * 4 + kk) * 64 + lane];  // lane-consecutive
                #pragma unroll
                for (int r = 0; r < 8; ++r)
                    acc[r] = __builtin_fmaf(xqf[r * 4 + kk], wv, acc[r]);
            }
        }

        if (t + 1 < A_NT) {
            stage_write((t + 1) & 1);        // vmcnt-waits on pf loads
            __syncthreads();                 // tile t+1 visible
            if (t + 2 < A_NT) stage_load(t + 2);   // issue early, hide under t+1
        }
    }

    #pragma unroll
    for (int r = 0; r < 8; ++r)
        ws[(size_t)(m0 + 8 * wu + r) * NU + n0 + lane] = acc[r];
}

// ---------------- Phase B: recurrence from t=2 (unchanged, proven) ---------
__global__ __launch_bounds__(BLK) void lif_recurrence(
    const float* __restrict__ x,
    const float* __restrict__ W,
    const float* __restrict__ V1,
    float* __restrict__ out)
{
    const int b    = blockIdx.x;
    const int tid  = threadIdx.x;
    const int lane = tid & 63;
    const int wid  = tid >> 6;

    __shared__ int           s_idx[NU];      // spiking row offsets (k*NU)
    __shared__ unsigned char s_flag[NU];
    __shared__ int           s_wsum[NWAVES];
    __shared__ int           s_cnt;

    const int n0 = tid;
    const int n1 = tid + BLK;

    float* outb = out + (size_t)b * TSTEPS * NU;   // (B, T, N)

    float V0, V1r;
    int   z0, z1;
    {
        float x0 = x[(size_t)b * NU + n0];
        float x1 = x[(size_t)b * NU + n1];
        outb[n0] = x0;
        outb[n1] = x1;
        V0  = V1[(size_t)b * NU + n0];
        V1r = V1[(size_t)b * NU + n1];
        z0 = V0  > 1.0f;
        z1 = V1r > 1.0f;
        float* f1 = outb + NU;
        f1[n0] = z0 ? 1.0f : 0.0f;
        f1[n1] = z1 ? 1.0f : 0.0f;
        s_flag[n0] = (unsigned char)z0;
        s_flag[n1] = (unsigned char)z1;
    }
    __syncthreads();

    for (int t = 2; t < TSTEPS; ++t) {
        int f0 = s_flag[2 * tid];
        int f1 = s_flag[2 * tid + 1];
        int c  = f0 + f1;
        int v  = c;
        #pragma unroll
        for (int d = 1; d < 64; d <<= 1) {
            int o = __shfl_up(v, d);
            if (lane >= d) v += o;
        }
        if (lane == 63) s_wsum[wid] = v;
        __syncthreads();
        int base = 0;
        #pragma unroll
        for (int w = 0; w < NWAVES; ++w) base += (w < wid) ? s_wsum[w] : 0;
        int off = base + v - c;                   // exclusive prefix
        if (f0) s_idx[off++] = (2 * tid) * NU;
        if (f1) s_idx[off]   = (2 * tid + 1) * NU;
        if (tid == BLK - 1) s_cnt = base + v;
        __syncthreads();

        int cnt = s_cnt;
        if (cnt == 0) {
            size_t  elems  = (size_t)(TSTEPS - t) * NU;
            float4* p      = (float4*)(outb + (size_t)t * NU);
            int     chunks = (int)(elems / 4);
            float4  zz; zz.x = zz.y = zz.z = zz.w = 0.0f;
            for (int i = tid; i < chunks; i += BLK) p[i] = zz;
            return;
        }

        float I0 = 0.0f, I1 = 0.0f;
        const float* Wc = W + tid;
        int i = 0;
        for (; i + 4 <= cnt; i += 4) {
            const float* r0 = Wc + s_idx[i];
            const float* r1 = Wc + s_idx[i + 1];
            const float* r2 = Wc + s_idx[i + 2];
            const float* r3 = Wc + s_idx[i + 3];
            float a0 = r0[0], b0 = r0[BLK];
            float a1 = r1[0], b1 = r1[BLK];
            float a2 = r2[0], b2 = r2[BLK];
            float a3 = r3[0], b3 = r3[BLK];
            I0 += a0; I0 += a1; I0 += a2; I0 += a3;   // order preserved
            I1 += b0; I1 += b1; I1 += b2; I1 += b3;
        }
        for (; i < cnt; ++i) {
            const float* r = Wc + s_idx[i];
            I0 += r[0];
            I1 += r[BLK];
        }

        float d0 = 0.90483741803595952f * V0;     // one rounding
        float d1 = 0.90483741803595952f * V1r;
        asm volatile("" : "+v"(d0), "+v"(d1));    // forbid fma-contraction
        float nv0 = (z0 ? 0.0f : d0) + I0;        // one rounding
        float nv1 = (z1 ? 0.0f : d1) + I1;
        V0 = nv0; V1r = nv1;
        z0 = nv0 > 1.0f;
        z1 = nv1 > 1.0f;

        float* po = outb + (size_t)t * NU;
        po[n0] = z0 ? 1.0f : 0.0f;
        po[n1] = z1 ? 1.0f : 0.0f;
        s_flag[n0] = (unsigned char)z0;
        s_flag[n1] = (unsigned char)z1;
        __syncthreads();
    }
}

// ---------------- Fallback: round-4 fused kernel (proven) ------------------
__global__ __launch_bounds__(BLK) void lif_fused(
    const float* __restrict__ x,
    const float* __restrict__ W,
    float* __restrict__ out)
{
    const int b    = blockIdx.x;
    const int tid  = threadIdx.x;
    const int lane = tid & 63;
    const int wid  = tid >> 6;

    __shared__ float         s_x[NU];
    __shared__ int           s_idx[NU];
    __shared__ unsigned char s_flag[NU];
    __shared__ int           s_wsum[NWAVES];
    __shared__ int           s_cnt;

    const int n0 = tid;
    const int n1 = tid + BLK;
    float* outb = out + (size_t)b * TSTEPS * NU;

    {
        float x0 = x[(size_t)b * NU + n0];
        float x1 = x[(size_t)b * NU + n1];
        s_x[n0] = x0; s_x[n1] = x1;
        outb[n0] = x0; outb[n1] = x1;
    }
    __syncthreads();

    float I0 = 0.0f, I1 = 0.0f;
    {
        const float* Wc = W + tid;
        #pragma unroll 8
        for (int k = 0; k < NU; ++k) {
            float xk = s_x[k];
            const float* wr = Wc + (size_t)k * NU;
            I0 = __builtin_fmaf(xk, wr[0],   I0);
            I1 = __builtin_fmaf(xk, wr[BLK], I1);
        }
    }

    float V0 = 0.0f, V1 = 0.0f;
    int   z0 = 0,    z1 = 0;

    for (int t = 1; t < TSTEPS; ++t) {
        if (t >= 2) {
            int f0 = s_flag[2 * tid];
            int f1 = s_flag[2 * tid + 1];
            int c  = f0 + f1;
            int v  = c;
            #pragma unroll
            for (int d = 1; d < 64; d <<= 1) {
                int o = __shfl_up(v, d);
                if (lane >= d) v += o;
            }
            if (lane == 63) s_wsum[wid] = v;
            __syncthreads();
            int base = 0;
            #pragma unroll
            for (int w = 0; w < NWAVES; ++w) base += (w < wid) ? s_wsum[w] : 0;
            int off = base + v - c;
            if (f0) s_idx[off++] = 2 * tid;
            if (f1) s_idx[off]   = 2 * tid + 1;
            if (tid == BLK - 1) s_cnt = base + v;
            __syncthreads();

            int cnt = s_cnt;
            if (cnt == 0) {
                size_t  elems  = (size_t)(TSTEPS - t) * NU;
                float4* p      = (float4*)(outb + (size_t)t * NU);
                int     chunks = (int)(elems / 4);
                float4  zz; zz.x = zz.y = zz.z = zz.w = 0.0f;
                for (int i = tid; i < chunks; i += BLK) p[i] = zz;
                return;
            }

            I0 = 0.0f; I1 = 0.0f;
            const float* Wc = W + tid;
            int i = 0;
            for (; i + 2 <= cnt; i += 2) {
                const float* r0 = Wc + (size_t)s_idx[i]     * NU;
                const float* r1 = Wc + (size_t)s_idx[i + 1] * NU;
                float a0 = r0[0], b0 = r0[BLK];
                float a1 = r1[0], b1 = r1[BLK];
                I0 += a0; I0 += a1;
                I1 += b0; I1 += b1;
            }
            for (; i < cnt; ++i) {
                const float* r = Wc + (size_t)s_idx[i] * NU;
                I0 += r[0];
                I1 += r[BLK];
            }
        }

        float d0 = 0.90483741803595952f * V0;
        float d1 = 0.90483741803595952f * V1;
        asm volatile("" : "+v"(d0), "+v"(d1));
        float nv0 = (z0 ? 0.0f : d0) + I0;
        float nv1 = (z1 ? 0.0f : d1) + I1;
        V0 = nv0; V1 = nv1;
        z0 = nv0 > 1.0f;
        z1 = nv1 > 1.0f;

        float* po = outb + (size_t)t * NU;
        po[n0] = z0 ? 1.0f : 0.0f;
        po[n1] = z1 ? 1.0f : 0.0f;
        s_flag[n0] = (unsigned char)z0;
        s_flag[n1] = (unsigned char)z1;
        __syncthreads();
    }
}

extern "C" void kernel_launch(void* const* d_in, const int* in_sizes, int n_in,
                              void* d_out, int out_size, void* d_ws, size_t ws_size,
                              hipStream_t stream) {
    const float* x = (const float*)d_in[0];   // (256, 2048) fp32
    const float* W = (const float*)d_in[1];   // (2048, 2048) fp32
    if (n_in >= 2 && in_sizes[0] == NU * NU && in_sizes[1] == BATCHSZ * NU) {
        const float* t = x; x = W; W = t;     // defensive input-order swap
    }
    float* out = (float*)d_out;               // (B, T, N) fp32

    const size_t need = (size_t)BATCHSZ * NU * sizeof(float);   // 2 MB
    if (ws_size >= need) {
        float* V1 = (float*)d_ws;
        hipLaunchKernelGGL(lif_dense_v1,
                           dim3(NU / 64, BATCHSZ / 16), dim3(128), 0, stream,
                           x, W, V1);
        hipLaunchKernelGGL(lif_recurrence,
                           dim3(BATCHSZ), dim3(BLK), 0, stream,
                           x, W, V1, out);
    } else {
        hipLaunchKernelGGL(lif_fused, dim3(BATCHSZ), dim3(BLK), 0, stream,
                           x, W, out);
    }
}

// Round 10
// 185.394 us; speedup vs baseline: 1.9394x; 1.9394x over previous
//
#include <hip/hip_runtime.h>
#include <stdint.h>

// LIF spike encoder — two-phase, bit-exact fp32.
//   Dense-phase history: R5 243us (2 waves/CU, latency) | R6 154us (8 waves/CU,
//   float4, XCD-local; L1-issue bound at 16.8 MB/CU) | R7 275us (XCD locality
//   broken, FETCH 4x) | R8 256us (float2: 2x load instrs, same bytes) |
//   R9 333us (LDS dedup, but 1 wave/SIMD + barriers = serialized).
//   Model: dense ~ L1-issued bytes/CU (45-64 B/cyc) + latency exposure when
//   waves/SIMD < 2 with barriers.
//   R10 (this): register-level W reuse. Each thread loads ONE W float4 and
//   feeds 2 rows (R=2 -> 8.4 MB/CU L1), two named prefetch banks bA/bB
//   (8 float4 in flight, no LDS, no barriers), x via wave-uniform scalar
//   path, n-fast grid keeps per-XCD W slice at 2 MB (L2-resident).
// Bit-exactness: each output = ONE register, fmaf over k=0..2047 ascending —
// identical chain to all passing rounds. Sparse phase: ordered adds over
// sorted spike list == dense chain exactly.

#define BATCHSZ 256
#define NU      2048
#define TSTEPS  128
#define BLK     1024
#define NWAVES  (BLK / 64)

// ---------------- Phase A: dense GEMM (t=1), bit-exact chain ----------------
// block 128 thr (2 waves); BM=4 rows x BN=256 cols; per thread 2 rows x 4 cols.
// grid (8 n-tiles FAST, 64 m-tiles) = 512 blocks -> 2/CU, xcd = n-tile%8.

__global__ __launch_bounds__(128) void lif_dense_v1(
    const float* __restrict__ x,
    const float* __restrict__ W,
    float* __restrict__ ws)
{
    const int tid  = threadIdx.x;
    const int lane = tid & 63;
    const int n0   = blockIdx.x * 256;      // n-tile fast -> per-XCD 2 MB slice
    const int m0   = blockIdx.y * 4;

    // wave-uniform row base -> scalar-path x loads
    const int rb = __builtin_amdgcn_readfirstlane((tid >> 6) * 2);  // 0 or 2
    const float* x0p = x + (size_t)(m0 + rb) * NU;
    const float* x1p = x0p + NU;

    const float* wp = W + n0 + lane * 4;    // this thread's 4 cols

    float4 bA[8], bB[8];                    // two prefetch banks (static idx)
    float acc0[4] = {0.f, 0.f, 0.f, 0.f};
    float acc1[4] = {0.f, 0.f, 0.f, 0.f};

    #pragma unroll
    for (int j = 0; j < 8; ++j)
        bA[j] = *(const float4*)(wp + (size_t)j * NU);

    for (int k0 = 0; k0 < NU; k0 += 16) {
        // prefetch k0+8..k0+15 (always in range: k0 <= 2032)
        #pragma unroll
        for (int j = 0; j < 8; ++j)
            bB[j] = *(const float4*)(wp + (size_t)(k0 + 8 + j) * NU);

        // compute k0..k0+7 from bA (k ascending)
        #pragma unroll
        for (int j = 0; j < 8; ++j) {
            float  xa = x0p[k0 + j];
            float  xb = x1p[k0 + j];
            float4 wv = bA[j];
            acc0[0] = __builtin_fmaf(xa, wv.x, acc0[0]);
            acc0[1] = __builtin_fmaf(xa, wv.y, acc0[1]);
            acc0[2] = __builtin_fmaf(xa, wv.z, acc0[2]);
            acc0[3] = __builtin_fmaf(xa, wv.w, acc0[3]);
            acc1[0] = __builtin_fmaf(xb, wv.x, acc1[0]);
            acc1[1] = __builtin_fmaf(xb, wv.y, acc1[1]);
            acc1[2] = __builtin_fmaf(xb, wv.z, acc1[2]);
            acc1[3] = __builtin_fmaf(xb, wv.w, acc1[3]);
        }

        // prefetch k0+16..k0+23
        if (k0 + 16 < NU) {
            #pragma unroll
            for (int j = 0; j < 8; ++j)
                bA[j] = *(const float4*)(wp + (size_t)(k0 + 16 + j) * NU);
        }

        // compute k0+8..k0+15 from bB (k ascending)
        #pragma unroll
        for (int j = 0; j < 8; ++j) {
            float  xa = x0p[k0 + 8 + j];
            float  xb = x1p[k0 + 8 + j];
            float4 wv = bB[j];
            acc0[0] = __builtin_fmaf(xa, wv.x, acc0[0]);
            acc0[1] = __builtin_fmaf(xa, wv.y, acc0[1]);
            acc0[2] = __builtin_fmaf(xa, wv.z, acc0[2]);
            acc0[3] = __builtin_fmaf(xa, wv.w, acc0[3]);
            acc1[0] = __builtin_fmaf(xb, wv.x, acc1[0]);
            acc1[1] = __builtin_fmaf(xb, wv.y, acc1[1]);
            acc1[2] = __builtin_fmaf(xb, wv.z, acc1[2]);
            acc1[3] = __builtin_fmaf(xb, wv.w, acc1[3]);
        }
    }

    float4 o0; o0.x = acc0[0]; o0.y = acc0[1]; o0.z = acc0[2]; o0.w = acc0[3];
    float4 o1; o1.x = acc1[0]; o1.y = acc1[1]; o1.z = acc1[2]; o1.w = acc1[3];
    *(float4*)&ws[(size_t)(m0 + rb)     * NU + n0 + lane * 4] = o0;
    *(float4*)&ws[(size_t)(m0 + rb + 1) * NU + n0 + lane * 4] = o1;
}

// ---------------- Phase B: recurrence from t=2 (unchanged, proven) ---------
__global__ __launch_bounds__(BLK) void lif_recurrence(
    const float* __restrict__ x,
    const float* __restrict__ W,
    const float* __restrict__ V1,
    float* __restrict__ out)
{
    const int b    = blockIdx.x;
    const int tid  = threadIdx.x;
    const int lane = tid & 63;
    const int wid  = tid >> 6;

    __shared__ int           s_idx[NU];      // spiking row offsets (k*NU)
    __shared__ unsigned char s_flag[NU];
    __shared__ int           s_wsum[NWAVES];
    __shared__ int           s_cnt;

    const int n0 = tid;
    const int n1 = tid + BLK;

    float* outb = out + (size_t)b * TSTEPS * NU;   // (B, T, N)

    float V0, V1r;
    int   z0, z1;
    {
        float x0 = x[(size_t)b * NU + n0];
        float x1 = x[(size_t)b * NU + n1];
        outb[n0] = x0;
        outb[n1] = x1;
        V0  = V1[(size_t)b * NU + n0];
        V1r = V1[(size_t)b * NU + n1];
        z0 = V0  > 1.0f;
        z1 = V1r > 1.0f;
        float* f1 = outb + NU;
        f1[n0] = z0 ? 1.0f : 0.0f;
        f1[n1] = z1 ? 1.0f : 0.0f;
        s_flag[n0] = (unsigned char)z0;
        s_flag[n1] = (unsigned char)z1;
    }
    __syncthreads();

    for (int t = 2; t < TSTEPS; ++t) {
        int f0 = s_flag[2 * tid];
        int f1 = s_flag[2 * tid + 1];
        int c  = f0 + f1;
        int v  = c;
        #pragma unroll
        for (int d = 1; d < 64; d <<= 1) {
            int o = __shfl_up(v, d);
            if (lane >= d) v += o;
        }
        if (lane == 63) s_wsum[wid] = v;
        __syncthreads();
        int base = 0;
        #pragma unroll
        for (int w = 0; w < NWAVES; ++w) base += (w < wid) ? s_wsum[w] : 0;
        int off = base + v - c;                   // exclusive prefix
        if (f0) s_idx[off++] = (2 * tid) * NU;
        if (f1) s_idx[off]   = (2 * tid + 1) * NU;
        if (tid == BLK - 1) s_cnt = base + v;
        __syncthreads();

        int cnt = s_cnt;
        if (cnt == 0) {
            size_t  elems  = (size_t)(TSTEPS - t) * NU;
            float4* p      = (float4*)(outb + (size_t)t * NU);
            int     chunks = (int)(elems / 4);
            float4  zz; zz.x = zz.y = zz.z = zz.w = 0.0f;
            for (int i = tid; i < chunks; i += BLK) p[i] = zz;
            return;
        }

        float I0 = 0.0f, I1 = 0.0f;
        const float* Wc = W + tid;
        int i = 0;
        for (; i + 4 <= cnt; i += 4) {
            const float* r0 = Wc + s_idx[i];
            const float* r1 = Wc + s_idx[i + 1];
            const float* r2 = Wc + s_idx[i + 2];
            const float* r3 = Wc + s_idx[i + 3];
            float a0 = r0[0], b0 = r0[BLK];
            float a1 = r1[0], b1 = r1[BLK];
            float a2 = r2[0], b2 = r2[BLK];
            float a3 = r3[0], b3 = r3[BLK];
            I0 += a0; I0 += a1; I0 += a2; I0 += a3;   // order preserved
            I1 += b0; I1 += b1; I1 += b2; I1 += b3;
        }
        for (; i < cnt; ++i) {
            const float* r = Wc + s_idx[i];
            I0 += r[0];
            I1 += r[BLK];
        }

        float d0 = 0.90483741803595952f * V0;     // one rounding
        float d1 = 0.90483741803595952f * V1r;
        asm volatile("" : "+v"(d0), "+v"(d1));    // forbid fma-contraction
        float nv0 = (z0 ? 0.0f : d0) + I0;        // one rounding
        float nv1 = (z1 ? 0.0f : d1) + I1;
        V0 = nv0; V1r = nv1;
        z0 = nv0 > 1.0f;
        z1 = nv1 > 1.0f;

        float* po = outb + (size_t)t * NU;
        po[n0] = z0 ? 1.0f : 0.0f;
        po[n1] = z1 ? 1.0f : 0.0f;
        s_flag[n0] = (unsigned char)z0;
        s_flag[n1] = (unsigned char)z1;
        __syncthreads();
    }
}

// ---------------- Fallback: round-4 fused kernel (proven) ------------------
__global__ __launch_bounds__(BLK) void lif_fused(
    const float* __restrict__ x,
    const float* __restrict__ W,
    float* __restrict__ out)
{
    const int b    = blockIdx.x;
    const int tid  = threadIdx.x;
    const int lane = tid & 63;
    const int wid  = tid >> 6;

    __shared__ float         s_x[NU];
    __shared__ int           s_idx[NU];
    __shared__ unsigned char s_flag[NU];
    __shared__ int           s_wsum[NWAVES];
    __shared__ int           s_cnt;

    const int n0 = tid;
    const int n1 = tid + BLK;
    float* outb = out + (size_t)b * TSTEPS * NU;

    {
        float x0 = x[(size_t)b * NU + n0];
        float x1 = x[(size_t)b * NU + n1];
        s_x[n0] = x0; s_x[n1] = x1;
        outb[n0] = x0; outb[n1] = x1;
    }
    __syncthreads();

    float I0 = 0.0f, I1 = 0.0f;
    {
        const float* Wc = W + tid;
        #pragma unroll 8
        for (int k = 0; k < NU; ++k) {
            float xk = s_x[k];
            const float* wr = Wc + (size_t)k * NU;
            I0 = __builtin_fmaf(xk, wr[0],   I0);
            I1 = __builtin_fmaf(xk, wr[BLK], I1);
        }
    }

    float V0 = 0.0f, V1 = 0.0f;
    int   z0 = 0,    z1 = 0;

    for (int t = 1; t < TSTEPS; ++t) {
        if (t >= 2) {
            int f0 = s_flag[2 * tid];
            int f1 = s_flag[2 * tid + 1];
            int c  = f0 + f1;
            int v  = c;
            #pragma unroll
            for (int d = 1; d < 64; d <<= 1) {
                int o = __shfl_up(v, d);
                if (lane >= d) v += o;
            }
            if (lane == 63) s_wsum[wid] = v;
            __syncthreads();
            int base = 0;
            #pragma unroll
            for (int w = 0; w < NWAVES; ++w) base += (w < wid) ? s_wsum[w] : 0;
            int off = base + v - c;
            if (f0) s_idx[off++] = 2 * tid;
            if (f1) s_idx[off]   = 2 * tid + 1;
            if (tid == BLK - 1) s_cnt = base + v;
            __syncthreads();

            int cnt = s_cnt;
            if (cnt == 0) {
                size_t  elems  = (size_t)(TSTEPS - t) * NU;
                float4* p      = (float4*)(outb + (size_t)t * NU);
                int     chunks = (int)(elems / 4);
                float4  zz; zz.x = zz.y = zz.z = zz.w = 0.0f;
                for (int i = tid; i < chunks; i += BLK) p[i] = zz;
                return;
            }

            I0 = 0.0f; I1 = 0.0f;
            const float* Wc = W + tid;
            int i = 0;
            for (; i + 2 <= cnt; i += 2) {
                const float* r0 = Wc + (size_t)s_idx[i]     * NU;
                const float* r1 = Wc + (size_t)s_idx[i + 1] * NU;
                float a0 = r0[0], b0 = r0[BLK];
                float a1 = r1[0], b1 = r1[BLK];
                I0 += a0; I0 += a1;
                I1 += b0; I1 += b1;
            }
            for (; i < cnt; ++i) {
                const float* r = Wc + (size_t)s_idx[i] * NU;
                I0 += r[0];
                I1 += r[BLK];
            }
        }

        float d0 = 0.90483741803595952f * V0;
        float d1 = 0.90483741803595952f * V1;
        asm volatile("" : "+v"(d0), "+v"(d1));
        float nv0 = (z0 ? 0.0f : d0) + I0;
        float nv1 = (z1 ? 0.0f : d1) + I1;
        V0 = nv0; V1 = nv1;
        z0 = nv0 > 1.0f;
        z1 = nv1 > 1.0f;

        float* po = outb + (size_t)t * NU;
        po[n0] = z0 ? 1.0f : 0.0f;
        po[n1] = z1 ? 1.0f : 0.0f;
        s_flag[n0] = (unsigned char)z0;
        s_flag[n1] = (unsigned char)z1;
        __syncthreads();
    }
}

extern "C" void kernel_launch(void* const* d_in, const int* in_sizes, int n_in,
                              void* d_out, int out_size, void* d_ws, size_t ws_size,
                              hipStream_t stream) {
    const float* x = (const float*)d_in[0];   // (256, 2048) fp32
    const float* W = (const float*)d_in[1];   // (2048, 2048) fp32
    if (n_in >= 2 && in_sizes[0] == NU * NU && in_sizes[1] == BATCHSZ * NU) {
        const float* t = x; x = W; W = t;     // defensive input-order swap
    }
    float* out = (float*)d_out;               // (B, T, N) fp32

    const size_t need = (size_t)BATCHSZ * NU * sizeof(float);   // 2 MB
    if (ws_size >= need) {
        float* V1 = (float*)d_ws;
        hipLaunchKernelGGL(lif_dense_v1,
                           dim3(NU / 256, BATCHSZ / 4), dim3(128), 0, stream,
                           x, W, V1);
        hipLaunchKernelGGL(lif_recurrence,
                           dim3(BATCHSZ), dim3(BLK), 0, stream,
                           x, W, V1, out);
    } else {
        hipLaunchKernelGGL(lif_fused, dim3(BATCHSZ), dim3(BLK), 0, stream,
                           x, W, out);
    }
}

// Round 11
// 181.484 us; speedup vs baseline: 1.9812x; 1.0215x over previous
//
#include <hip/hip_runtime.h>
#include <stdint.h>

// LIF spike encoder — two-phase, bit-exact fp32.
//   Dense history: R5 243 | R6 154 (XCD-local n-fast grid, 16.8 MB/CU L1) |
//   R7 275 (broke XCD locality) | R8 256 | R9 333 (LDS+barriers @1 wave/SIMD) |
//   R10 ~125 in 185 total (reg-dbuf R=2, 8.4 MB/CU, bank depth 8 < L2 lat).
//   Model: dense ~= max(L1 bytes/CU / ~60 B/cyc, VALU) + exposed latency.
//   R11 (this): R=4 rows/thread x float2 cols (halves L1 bytes to 4.2 MB/CU,
//   same 1024-wave occupancy and 1 load-instr/k), banks deepened to 16 k so
//   compute (256 cyc) covers L2 latency (~200). Grid (16 n-fast x 32 m):
//   2 blocks/CU, per-XCD W slice 2 MB (L2-resident invariant).
// Bit-exactness: each output = ONE register, one fmaf per k, k=0..2047
// ascending — identical chain to all passing rounds. Sparse phase: ordered
// adds over sorted spike list == dense chain exactly.

#define BATCHSZ 256
#define NU      2048
#define TSTEPS  128
#define BLK     1024
#define NWAVES  (BLK / 64)

// ---------------- Phase A: dense GEMM (t=1), bit-exact chain ----------------
// block 128 thr (2 waves); BM=8 rows (4/wave) x BN=128 cols (2/lane).
#define D_BN 128
#define D_BM 8

__global__ __launch_bounds__(128) void lif_dense_v1(
    const float* __restrict__ x,
    const float* __restrict__ W,
    float* __restrict__ ws)
{
    const int tid  = threadIdx.x;
    const int lane = tid & 63;
    const int n0   = blockIdx.x * D_BN;     // n-tile FAST -> xcd = bid%8
    const int m0   = blockIdx.y * D_BM;

    // wave-uniform row base -> scalar-path x loads
    const int rb = __builtin_amdgcn_readfirstlane((tid >> 6) * 4);  // 0 or 4
    const float* xb = x + (size_t)(m0 + rb) * NU;

    const float* wp = W + n0 + lane * 2;    // this thread's 2 cols

    float2 bA[16], bB[16];                  // two 16-deep prefetch banks
    float2 acc[4];
    #pragma unroll
    for (int r = 0; r < 4; ++r) { acc[r].x = 0.0f; acc[r].y = 0.0f; }

    #pragma unroll
    for (int j = 0; j < 16; ++j)            // preload k = 0..15
        bA[j] = *(const float2*)(wp + (size_t)j * NU);

    for (int k0 = 0; k0 < NU; k0 += 32) {
        // prefetch k0+16..k0+31 into bB (always in range)
        #pragma unroll
        for (int j = 0; j < 16; ++j)
            bB[j] = *(const float2*)(wp + (size_t)(k0 + 16 + j) * NU);

        // compute k0..k0+15 from bA (k ascending; 4 sub-phases of 4 k)
        #pragma unroll
        for (int q = 0; q < 4; ++q) {
            float4 xq[4];
            #pragma unroll
            for (int r = 0; r < 4; ++r)
                xq[r] = *(const float4*)(xb + (size_t)r * NU + k0 + q * 4);
            #pragma unroll
            for (int kk = 0; kk < 4; ++kk) {
                float2 wv = bA[q * 4 + kk];
                const float* xf = (const float*)&xq[0];
                #pragma unroll
                for (int r = 0; r < 4; ++r) {
                    float xv = xf[r * 4 + kk];
                    acc[r].x = __builtin_fmaf(xv, wv.x, acc[r].x);
                    acc[r].y = __builtin_fmaf(xv, wv.y, acc[r].y);
                }
            }
        }

        // prefetch k0+32..k0+47 into bA
        if (k0 + 32 < NU) {
            #pragma unroll
            for (int j = 0; j < 16; ++j)
                bA[j] = *(const float2*)(wp + (size_t)(k0 + 32 + j) * NU);
        }

        // compute k0+16..k0+31 from bB
        #pragma unroll
        for (int q = 0; q < 4; ++q) {
            float4 xq[4];
            #pragma unroll
            for (int r = 0; r < 4; ++r)
                xq[r] = *(const float4*)(xb + (size_t)r * NU + k0 + 16 + q * 4);
            #pragma unroll
            for (int kk = 0; kk < 4; ++kk) {
                float2 wv = bB[q * 4 + kk];
                const float* xf = (const float*)&xq[0];
                #pragma unroll
                for (int r = 0; r < 4; ++r) {
                    float xv = xf[r * 4 + kk];
                    acc[r].x = __builtin_fmaf(xv, wv.x, acc[r].x);
                    acc[r].y = __builtin_fmaf(xv, wv.y, acc[r].y);
                }
            }
        }
    }

    #pragma unroll
    for (int r = 0; r < 4; ++r)
        *(float2*)&ws[(size_t)(m0 + rb + r) * NU + n0 + lane * 2] = acc[r];
}

// ---------------- Phase B: recurrence from t=2 (unchanged, proven) ---------
__global__ __launch_bounds__(BLK) void lif_recurrence(
    const float* __restrict__ x,
    const float* __restrict__ W,
    const float* __restrict__ V1,
    float* __restrict__ out)
{
    const int b    = blockIdx.x;
    const int tid  = threadIdx.x;
    const int lane = tid & 63;
    const int wid  = tid >> 6;

    __shared__ int           s_idx[NU];      // spiking row offsets (k*NU)
    __shared__ unsigned char s_flag[NU];
    __shared__ int           s_wsum[NWAVES];
    __shared__ int           s_cnt;

    const int n0 = tid;
    const int n1 = tid + BLK;

    float* outb = out + (size_t)b * TSTEPS * NU;   // (B, T, N)

    float V0, V1r;
    int   z0, z1;
    {
        float x0 = x[(size_t)b * NU + n0];
        float x1 = x[(size_t)b * NU + n1];
        outb[n0] = x0;
        outb[n1] = x1;
        V0  = V1[(size_t)b * NU + n0];
        V1r = V1[(size_t)b * NU + n1];
        z0 = V0  > 1.0f;
        z1 = V1r > 1.0f;
        float* f1 = outb + NU;
        f1[n0] = z0 ? 1.0f : 0.0f;
        f1[n1] = z1 ? 1.0f : 0.0f;
        s_flag[n0] = (unsigned char)z0;
        s_flag[n1] = (unsigned char)z1;
    }
    __syncthreads();

    for (int t = 2; t < TSTEPS; ++t) {
        int f0 = s_flag[2 * tid];
        int f1 = s_flag[2 * tid + 1];
        int c  = f0 + f1;
        int v  = c;
        #pragma unroll
        for (int d = 1; d < 64; d <<= 1) {
            int o = __shfl_up(v, d);
            if (lane >= d) v += o;
        }
        if (lane == 63) s_wsum[wid] = v;
        __syncthreads();
        int base = 0;
        #pragma unroll
        for (int w = 0; w < NWAVES; ++w) base += (w < wid) ? s_wsum[w] : 0;
        int off = base + v - c;                   // exclusive prefix
        if (f0) s_idx[off++] = (2 * tid) * NU;
        if (f1) s_idx[off]   = (2 * tid + 1) * NU;
        if (tid == BLK - 1) s_cnt = base + v;
        __syncthreads();

        int cnt = s_cnt;
        if (cnt == 0) {
            size_t  elems  = (size_t)(TSTEPS - t) * NU;
            float4* p      = (float4*)(outb + (size_t)t * NU);
            int     chunks = (int)(elems / 4);
            float4  zz; zz.x = zz.y = zz.z = zz.w = 0.0f;
            for (int i = tid; i < chunks; i += BLK) p[i] = zz;
            return;
        }

        float I0 = 0.0f, I1 = 0.0f;
        const float* Wc = W + tid;
        int i = 0;
        for (; i + 4 <= cnt; i += 4) {
            const float* r0 = Wc + s_idx[i];
            const float* r1 = Wc + s_idx[i + 1];
            const float* r2 = Wc + s_idx[i + 2];
            const float* r3 = Wc + s_idx[i + 3];
            float a0 = r0[0], b0 = r0[BLK];
            float a1 = r1[0], b1 = r1[BLK];
            float a2 = r2[0], b2 = r2[BLK];
            float a3 = r3[0], b3 = r3[BLK];
            I0 += a0; I0 += a1; I0 += a2; I0 += a3;   // order preserved
            I1 += b0; I1 += b1; I1 += b2; I1 += b3;
        }
        for (; i < cnt; ++i) {
            const float* r = Wc + s_idx[i];
            I0 += r[0];
            I1 += r[BLK];
        }

        float d0 = 0.90483741803595952f * V0;     // one rounding
        float d1 = 0.90483741803595952f * V1r;
        asm volatile("" : "+v"(d0), "+v"(d1));    // forbid fma-contraction
        float nv0 = (z0 ? 0.0f : d0) + I0;        // one rounding
        float nv1 = (z1 ? 0.0f : d1) + I1;
        V0 = nv0; V1r = nv1;
        z0 = nv0 > 1.0f;
        z1 = nv1 > 1.0f;

        float* po = outb + (size_t)t * NU;
        po[n0] = z0 ? 1.0f : 0.0f;
        po[n1] = z1 ? 1.0f : 0.0f;
        s_flag[n0] = (unsigned char)z0;
        s_flag[n1] = (unsigned char)z1;
        __syncthreads();
    }
}

// ---------------- Fallback: round-4 fused kernel (proven) ------------------
__global__ __launch_bounds__(BLK) void lif_fused(
    const float* __restrict__ x,
    const float* __restrict__ W,
    float* __restrict__ out)
{
    const int b    = blockIdx.x;
    const int tid  = threadIdx.x;
    const int lane = tid & 63;
    const int wid  = tid >> 6;

    __shared__ float         s_x[NU];
    __shared__ int           s_idx[NU];
    __shared__ unsigned char s_flag[NU];
    __shared__ int           s_wsum[NWAVES];
    __shared__ int           s_cnt;

    const int n0 = tid;
    const int n1 = tid + BLK;
    float* outb = out + (size_t)b * TSTEPS * NU;

    {
        float x0 = x[(size_t)b * NU + n0];
        float x1 = x[(size_t)b * NU + n1];
        s_x[n0] = x0; s_x[n1] = x1;
        outb[n0] = x0; outb[n1] = x1;
    }
    __syncthreads();

    float I0 = 0.0f, I1 = 0.0f;
    {
        const float* Wc = W + tid;
        #pragma unroll 8
        for (int k = 0; k < NU; ++k) {
            float xk = s_x[k];
            const float* wr = Wc + (size_t)k * NU;
            I0 = __builtin_fmaf(xk, wr[0],   I0);
            I1 = __builtin_fmaf(xk, wr[BLK], I1);
        }
    }

    float V0 = 0.0f, V1 = 0.0f;
    int   z0 = 0,    z1 = 0;

    for (int t = 1; t < TSTEPS; ++t) {
        if (t >= 2) {
            int f0 = s_flag[2 * tid];
            int f1 = s_flag[2 * tid + 1];
            int c  = f0 + f1;
            int v  = c;
            #pragma unroll
            for (int d = 1; d < 64; d <<= 1) {
                int o = __shfl_up(v, d);
                if (lane >= d) v += o;
            }
            if (lane == 63) s_wsum[wid] = v;
            __syncthreads();
            int base = 0;
            #pragma unroll
            for (int w = 0; w < NWAVES; ++w) base += (w < wid) ? s_wsum[w] : 0;
            int off = base + v - c;
            if (f0) s_idx[off++] = 2 * tid;
            if (f1) s_idx[off]   = 2 * tid + 1;
            if (tid == BLK - 1) s_cnt = base + v;
            __syncthreads();

            int cnt = s_cnt;
            if (cnt == 0) {
                size_t  elems  = (size_t)(TSTEPS - t) * NU;
                float4* p      = (float4*)(outb + (size_t)t * NU);
                int     chunks = (int)(elems / 4);
                float4  zz; zz.x = zz.y = zz.z = zz.w = 0.0f;
                for (int i = tid; i < chunks; i += BLK) p[i] = zz;
                return;
            }

            I0 = 0.0f; I1 = 0.0f;
            const float* Wc = W + tid;
            int i = 0;
            for (; i + 2 <= cnt; i += 2) {
                const float* r0 = Wc + (size_t)s_idx[i]     * NU;
                const float* r1 = Wc + (size_t)s_idx[i + 1] * NU;
                float a0 = r0[0], b0 = r0[BLK];
                float a1 = r1[0], b1 = r1[BLK];
                I0 += a0; I0 += a1;
                I1 += b0; I1 += b1;
            }
            for (; i < cnt; ++i) {
                const float* r = Wc + (size_t)s_idx[i] * NU;
                I0 += r[0];
                I1 += r[BLK];
            }
        }

        float d0 = 0.90483741803595952f * V0;
        float d1 = 0.90483741803595952f * V1;
        asm volatile("" : "+v"(d0), "+v"(d1));
        float nv0 = (z0 ? 0.0f : d0) + I0;
        float nv1 = (z1 ? 0.0f : d1) + I1;
        V0 = nv0; V1 = nv1;
        z0 = nv0 > 1.0f;
        z1 = nv1 > 1.0f;

        float* po = outb + (size_t)t * NU;
        po[n0] = z0 ? 1.0f : 0.0f;
        po[n1] = z1 ? 1.0f : 0.0f;
        s_flag[n0] = (unsigned char)z0;
        s_flag[n1] = (unsigned char)z1;
        __syncthreads();
    }
}

extern "C" void kernel_launch(void* const* d_in, const int* in_sizes, int n_in,
                              void* d_out, int out_size, void* d_ws, size_t ws_size,
                              hipStream_t stream) {
    const float* x = (const float*)d_in[0];   // (256, 2048) fp32
    const float* W = (const float*)d_in[1];   // (2048, 2048) fp32
    if (n_in >= 2 && in_sizes[0] == NU * NU && in_sizes[1] == BATCHSZ * NU) {
        const float* t = x; x = W; W = t;     // defensive input-order swap
    }
    float* out = (float*)d_out;               // (B, T, N) fp32

    const size_t need = (size_t)BATCHSZ * NU * sizeof(float);   // 2 MB
    if (ws_size >= need) {
        float* V1 = (float*)d_ws;
        hipLaunchKernelGGL(lif_dense_v1,
                           dim3(NU / D_BN, BATCHSZ / D_BM), dim3(128), 0, stream,
                           x, W, V1);
        hipLaunchKernelGGL(lif_recurrence,
                           dim3(BATCHSZ), dim3(BLK), 0, stream,
                           x, W, V1, out);
    } else {
        hipLaunchKernelGGL(lif_fused, dim3(BATCHSZ), dim3(BLK), 0, stream,
                           x, W, out);
    }
}